// Round 4
// baseline (764.768 us; speedup 1.0000x reference)
//
#include <hip/hip_runtime.h>

// BetaBernoulliMixture: per row r, per time t:
//   s_prev = #ones in obs[r, 0..t-1];  f_prev = t - s_prev
//   a1 = alpha1+s_prev, b1 = beta1+f_prev, a2 = alpha2+s_prev, b2 = beta2+f_prev
//   d(t) = sum_{u<t} [ log(sel2_u*(AB1+u)) - log(sel1_u*(AB2+u)) ]
//   post_mixweight = w / (w + (1-w)*exp(d))
// Output layout: [5, B, T] = {a1, b1, a2, b2, post_mixweight}
//
// R4 structure: ONE WAVE PER ROW (4 rows per 256-thread block). No LDS, no
// __syncthreads -> no vmcnt(0) store-queue drains (R3's residual cost: each
// barrier forced all outstanding NT stores to ACK, 16x per block). Bit cumsum
// via ballot+popc (no dependency chain); delta cumsum via in-wave shuffle
// scan. Lane-contiguous float4 NT stores (full 32B sectors, no RFO, no
// amplification). Param outputs (a1,b1,a2,b2) are stored BEFORE the delta
// scan chain so their traffic overlaps the shuffle latency.

#define BLOCK 256
#define VEC 4

typedef float v4f __attribute__((ext_vector_type(4)));

__global__ __launch_bounds__(BLOCK) void bbm_kernel(
    const float* __restrict__ obs,
    const float* __restrict__ alpha1, const float* __restrict__ beta1,
    const float* __restrict__ alpha2, const float* __restrict__ beta2,
    const float* __restrict__ mixw,
    float* __restrict__ out,
    int T, size_t bt)
{
    const int lane = threadIdx.x & 63;
    const int wid  = threadIdx.x >> 6;
    const int row  = blockIdx.x * 4 + wid;

    const float A1 = alpha1[row], B1 = beta1[row];
    const float A2 = alpha2[row], B2 = beta2[row];
    const float w  = mixw[0];
    const float AB1 = A1 + B1, AB2 = A2 + B2;
    const float w2 = 1.0f - w;

    const float* __restrict__ orow = obs + (size_t)row * T;
    float* __restrict__ obase = out + (size_t)row * T;

    const unsigned long long lt_mask = ((unsigned long long)1 << lane) - 1;

    int   carry_s = 0;
    float carry_d = 0.0f;

    const int SEG  = 64 * VEC;          // 256 elems per wave-segment
    const int segs = T / SEG;           // 32 for T=8192

    v4f cur = *(const v4f*)(orow + lane * VEC);

    for (int seg = 0; seg < segs; ++seg) {
        const int t0 = seg * SEG + lane * VEC;

        // prefetch next segment's obs (overlaps everything below)
        v4f nxt;
        if (seg + 1 < segs) nxt = *(const v4f*)(orow + (seg + 1) * SEG + lane * VEC);

        // ---- bits + thread-local exclusive prefix ----
        int bit[VEC], sloc[VEC];
        int ts = 0;
        #pragma unroll
        for (int j = 0; j < VEC; ++j) { bit[j] = cur[j] > 0.5f; sloc[j] = ts; ts += bit[j]; }

        // ---- in-wave bit scan via ballot+popc (no serial chain) ----
        unsigned long long m0 = __ballot(bit[0]);
        unsigned long long m1 = __ballot(bit[1]);
        unsigned long long m2 = __ballot(bit[2]);
        unsigned long long m3 = __ballot(bit[3]);
        const int wave_excl = __builtin_popcountll(m0 & lt_mask)
                            + __builtin_popcountll(m1 & lt_mask)
                            + __builtin_popcountll(m2 & lt_mask)
                            + __builtin_popcountll(m3 & lt_mask);
        const int wave_tot  = __builtin_popcountll(m0) + __builtin_popcountll(m1)
                            + __builtin_popcountll(m2) + __builtin_popcountll(m3);
        const int tbase_s = carry_s + wave_excl;

        // ---- posterior params; store 4 streams BEFORE the delta chain ----
        float fsv[VEC], fpv[VEC];
        v4f va1, vb1, va2, vb2;
        #pragma unroll
        for (int j = 0; j < VEC; ++j) {
            const float ft = (float)(t0 + j);
            const float fs = (float)(tbase_s + sloc[j]);
            const float fp = ft - fs;
            fsv[j] = fs; fpv[j] = fp;
            va1[j] = A1 + fs;
            vb1[j] = B1 + fp;
            va2[j] = A2 + fs;
            vb2[j] = B2 + fp;
        }
        float* p = obase + t0;
        __builtin_nontemporal_store(va1, (v4f*)(p));
        __builtin_nontemporal_store(vb1, (v4f*)(p + bt));
        __builtin_nontemporal_store(va2, (v4f*)(p + 2 * bt));
        __builtin_nontemporal_store(vb2, (v4f*)(p + 3 * bt));

        // ---- per-elem delta + thread-local exclusive prefix ----
        float dloc[VEC];
        float td = 0.0f;
        #pragma unroll
        for (int j = 0; j < VEC; ++j) {
            const float ft = (float)(t0 + j);
            const float sel1 = bit[j] ? (A1 + fsv[j]) : (B1 + fpv[j]);
            const float sel2 = bit[j] ? (A2 + fsv[j]) : (B2 + fpv[j]);
            const float delta = __logf(sel2 * (AB1 + ft)) - __logf(sel1 * (AB2 + ft));
            dloc[j] = td;
            td += delta;
        }

        // ---- in-wave shuffle scan over thread delta totals ----
        float incl_d = td;
        #pragma unroll
        for (int off = 1; off < 64; off <<= 1) {
            float n = __shfl_up(incl_d, off, 64);
            if (lane >= off) incl_d += n;
        }
        const float tbase_d  = carry_d + (incl_d - td);
        const float total_d  = __shfl(incl_d, 63, 64);

        // ---- mixweight stream ----
        v4f vpm;
        #pragma unroll
        for (int j = 0; j < VEC; ++j) {
            const float d = tbase_d + dloc[j];
            vpm[j] = w / (w + w2 * __expf(d));
        }
        __builtin_nontemporal_store(vpm, (v4f*)(p + 4 * bt));

        carry_s += wave_tot;
        carry_d += total_d;
        cur = nxt;
    }
}

extern "C" void kernel_launch(void* const* d_in, const int* in_sizes, int n_in,
                              void* d_out, int out_size, void* d_ws, size_t ws_size,
                              hipStream_t stream) {
    const float* obs    = (const float*)d_in[0];
    const float* alpha1 = (const float*)d_in[1];
    const float* beta1  = (const float*)d_in[2];
    const float* alpha2 = (const float*)d_in[3];
    const float* beta2  = (const float*)d_in[4];
    const float* mixw   = (const float*)d_in[5];

    const int Bn = in_sizes[1];
    const int Tn = in_sizes[0] / Bn;
    const size_t bt = (size_t)Bn * (size_t)Tn;

    bbm_kernel<<<Bn / 4, BLOCK, 0, stream>>>(obs, alpha1, beta1, alpha2, beta2,
                                             mixw, (float*)d_out, Tn, bt);
}